// Round 8
// baseline (216.290 us; speedup 1.0000x reference)
//
#include <hip/hip_runtime.h>
#include <math.h>

typedef __bf16 bf16;
typedef __attribute__((ext_vector_type(8))) __bf16 bf16x8;
typedef __attribute__((ext_vector_type(4))) __bf16 bf16x4;
typedef __attribute__((ext_vector_type(4))) float f32x4;

#define B_  2
#define S_  2048
#define H_  1024
#define NH_ 16
#define D_  64

__device__ __forceinline__ f32x4 mfma16(bf16x8 a, bf16x8 b, f32x4 c) {
    return __builtin_amdgcn_mfma_f32_16x16x32_bf16(a, b, c, 0, 0, 0);
}

// async global->LDS, 16B per lane; lds dest = wave-uniform base + lane*16
__device__ __forceinline__ void async16(void* lds, const void* g) {
    __builtin_amdgcn_global_load_lds(
        (const __attribute__((address_space(1))) unsigned int*)g,
        (__attribute__((address_space(3))) unsigned int*)lds, 16, 0, 0);
}

// Merged prep: cvt x -> xb, cvt Wqkv -> wqb, build RoPE table tab[s][i]={cos,sin}
__global__ __launch_bounds__(256) void cvt_main(
    const float* __restrict__ x, const float* __restrict__ wqkv,
    bf16* __restrict__ xb, bf16* __restrict__ wqb, float2* __restrict__ tab)
{
    const int bid = blockIdx.x, tid = threadIdx.x;
    if (bid < 4096) {
        int i = bid * 256 + tid;
        f32x4 v = *(const f32x4*)(x + (size_t)i * 4);
        bf16x4 o; o[0]=(bf16)v[0]; o[1]=(bf16)v[1]; o[2]=(bf16)v[2]; o[3]=(bf16)v[3];
        *(bf16x4*)(xb + (size_t)i * 4) = o;
    } else if (bid < 7168) {
        int i = (bid - 4096) * 256 + tid;
        f32x4 v = *(const f32x4*)(wqkv + (size_t)i * 4);
        bf16x4 o; o[0]=(bf16)v[0]; o[1]=(bf16)v[1]; o[2]=(bf16)v[2]; o[3]=(bf16)v[3];
        *(bf16x4*)(wqb + (size_t)i * 4) = o;
    } else {
        int idx = (bid - 7168) * 256 + tid;      // idx = s*32 + i
        int s = idx >> 5, i = idx & 31;
        float f = exp2f((float)i * (-13.287712379549449f / 32.0f));
        float sn, cs;
        sincosf((float)s * f, &sn, &cs);
        tab[idx] = make_float2(cs, sn);
    }
}

// fp32 -> bf16 bulk convert (W_o), 4 elems/thread
__global__ __launch_bounds__(256) void cvt_bf16(const float* __restrict__ src,
                                                bf16* __restrict__ dst, int n4) {
    int i = blockIdx.x * 256 + threadIdx.x;
    if (i >= n4) return;
    f32x4 v = *(const f32x4*)(src + (size_t)i * 4);
    bf16x4 o; o[0]=(bf16)v[0]; o[1]=(bf16)v[1]; o[2]=(bf16)v[2]; o[3]=(bf16)v[3];
    *(bf16x4*)(dst + (size_t)i * 4) = o;
}

// ---------------------------------------------------------------------------
// qkv GEMM — measured-best round-3 form: 256x256 tile, BK=64, 8 waves
// (2M x 4N), 4-phase K-loop with counted vmcnt, XCD-aware bijective remap.
// Epilogue: fused RMSNorm + table-RoPE (q,k), lambda-mix + transposed v.
// ---------------------------------------------------------------------------
__global__ __launch_bounds__(512, 2) void gemm_qkv(
    const bf16* __restrict__ A, const bf16* __restrict__ W,
    bf16* __restrict__ qb, bf16* __restrict__ kb, bf16* __restrict__ vtb,
    const float* __restrict__ ve, const float* __restrict__ lambdas,
    const float2* __restrict__ tab)
{
    constexpr int K  = H_;        // 1024
    constexpr int NS = K >> 6;    // 16 K-tiles
    __shared__ bf16 Al[2][256][64];
    __shared__ bf16 Bl[2][256][64];
    const int id = blockIdx.x + 12 * blockIdx.y;    // 0..191
    const int rX = id & 7, qX = id >> 3;            // qX in 0..23
    const int m0 = ((rX >> 2) * 8 + qX / 3) * 256;
    const int n0 = ((rX & 3) * 3 + qX % 3) * 256;
    const int tid  = threadIdx.x;
    const int lane = tid & 63;
    const int w    = tid >> 6;          // 0..7
    const int quad = lane >> 4;
    const int l16  = lane & 15;
    const int l7r  = l16 & 7;
    const int wm   = (w >> 2) * 128;    // wave M-offset (0 or 128)
    const int wn   = (w & 3) * 64;      // wave N-offset (0/64/128/192)
    const int r8   = lane >> 3;
    const int cs   = ((lane & 7) ^ r8) * 8;   // swizzled source col (elems)

    // stage half-tile h (0=A0,1=A1,2=B0,3=B1) of K-tile kt into slot sl
    auto stage_half = [&](int sl, int kt, int h) {
        const int k0 = kt << 6;
        if (h < 2) {
            const bf16* g = A + (size_t)(m0 + h * 128 + w * 16 + r8) * K + k0 + cs;
            async16(&Al[sl][h * 128 + w * 16][0],     g);
            async16(&Al[sl][h * 128 + w * 16 + 8][0], g + (size_t)8 * K);
        } else {
            const bf16* g = W + (size_t)(n0 + (h - 2) * 128 + w * 16 + r8) * K + k0 + cs;
            async16(&Bl[sl][(h - 2) * 128 + w * 16][0],     g);
            async16(&Bl[sl][(h - 2) * 128 + w * 16 + 8][0], g + (size_t)8 * K);
        }
    };

    const f32x4 Z4 = {0.f, 0.f, 0.f, 0.f};
    f32x4 acc[8][4];
#pragma unroll
    for (int i = 0; i < 8; ++i)
#pragma unroll
        for (int j = 0; j < 4; ++j) acc[i][j] = Z4;

    // prologue: tile0 fully + tile1's first half (stream position -1)
    stage_half(0, 0, 0); stage_half(0, 0, 1); stage_half(0, 0, 2); stage_half(0, 0, 3);
    stage_half(1, (NS > 1 ? 1 : 0), 0);

    for (int t = 0; t < NS; ++t) {
        const int cur = t & 1;
        const int kt1 = (t + 1 < NS) ? t + 1 : NS - 1;
        const int kt2 = (t + 2 < NS) ? t + 2 : NS - 1;
        bf16x8 aL[4][2], aH[4][2], bq0[2][2], bq1[2][2];

        // ---- phase 0: wait tile t landed (keep next tile's A0 in flight)
        asm volatile("s_waitcnt vmcnt(2)" ::: "memory");
        __builtin_amdgcn_s_barrier();
#pragma unroll
        for (int ks = 0; ks < 2; ++ks) {
#pragma unroll
            for (int i = 0; i < 4; ++i)
                aL[i][ks] = *(const bf16x8*)
                    &Al[cur][wm + i * 16 + l16][(((ks << 2) + quad) ^ l7r) * 8];
#pragma unroll
            for (int j = 0; j < 2; ++j)
                bq0[j][ks] = *(const bf16x8*)
                    &Bl[cur][wn + j * 16 + l16][(((ks << 2) + quad) ^ l7r) * 8];
        }
        stage_half(cur ^ 1, kt1, 1);
        __builtin_amdgcn_s_setprio(1);
#pragma unroll
        for (int ks = 0; ks < 2; ++ks)
#pragma unroll
            for (int i = 0; i < 4; ++i)
#pragma unroll
                for (int j = 0; j < 2; ++j)
                    acc[i][j] = mfma16(aL[i][ks], bq0[j][ks], acc[i][j]);
        __builtin_amdgcn_s_setprio(0);

        // ---- phase 1
        __builtin_amdgcn_s_barrier();
#pragma unroll
        for (int ks = 0; ks < 2; ++ks)
#pragma unroll
            for (int j = 0; j < 2; ++j)
                bq1[j][ks] = *(const bf16x8*)
                    &Bl[cur][wn + 32 + j * 16 + l16][(((ks << 2) + quad) ^ l7r) * 8];
        stage_half(cur ^ 1, kt1, 2);
        __builtin_amdgcn_s_setprio(1);
#pragma unroll
        for (int ks = 0; ks < 2; ++ks)
#pragma unroll
            for (int i = 0; i < 4; ++i)
#pragma unroll
                for (int j = 0; j < 2; ++j)
                    acc[i][2 + j] = mfma16(aL[i][ks], bq1[j][ks], acc[i][2 + j]);
        __builtin_amdgcn_s_setprio(0);

        // ---- phase 2
        __builtin_amdgcn_s_barrier();
#pragma unroll
        for (int ks = 0; ks < 2; ++ks)
#pragma unroll
            for (int i = 0; i < 4; ++i)
                aH[i][ks] = *(const bf16x8*)
                    &Al[cur][wm + 64 + i * 16 + l16][(((ks << 2) + quad) ^ l7r) * 8];
        stage_half(cur ^ 1, kt1, 3);
        __builtin_amdgcn_s_setprio(1);
#pragma unroll
        for (int ks = 0; ks < 2; ++ks)
#pragma unroll
            for (int i = 0; i < 4; ++i)
#pragma unroll
                for (int j = 0; j < 2; ++j)
                    acc[4 + i][j] = mfma16(aH[i][ks], bq0[j][ks], acc[4 + i][j]);
        __builtin_amdgcn_s_setprio(0);

        // ---- phase 3
        __builtin_amdgcn_s_barrier();
        stage_half(cur, kt2, 0);
        __builtin_amdgcn_s_setprio(1);
#pragma unroll
        for (int ks = 0; ks < 2; ++ks)
#pragma unroll
            for (int i = 0; i < 4; ++i)
#pragma unroll
                for (int j = 0; j < 2; ++j)
                    acc[4 + i][2 + j] = mfma16(aH[i][ks], bq1[j][ks], acc[4 + i][2 + j]);
        __builtin_amdgcn_s_setprio(0);
    }
    asm volatile("s_waitcnt vmcnt(0)" ::: "memory");   // drain clamped tail stages

    // ---- fused epilogue
    const int nbase = n0 + wn;              // wave-uniform, 64-aligned
    const int which = nbase >> 10;          // 0=q 1=k 2=v
    const int h     = (nbase & (H_ - 1)) >> 6;
    if (which < 2) {
        bf16* dst = which ? kb : qb;
#pragma unroll
        for (int i = 0; i < 8; ++i) {
            float ss[4];
#pragma unroll
            for (int r = 0; r < 4; ++r)
                ss[r] = acc[i][0][r] * acc[i][0][r] + acc[i][1][r] * acc[i][1][r]
                      + acc[i][2][r] * acc[i][2][r] + acc[i][3][r] * acc[i][3][r];
#pragma unroll
            for (int r = 0; r < 4; ++r) {
                ss[r] += __shfl_xor(ss[r], 1);
                ss[r] += __shfl_xor(ss[r], 2);
                ss[r] += __shfl_xor(ss[r], 4);
                ss[r] += __shfl_xor(ss[r], 8);
            }
#pragma unroll
            for (int r = 0; r < 4; ++r) {
                int    m   = m0 + wm + i * 16 + quad * 4 + r;
                int    bb  = m >> 11, s = m & (S_ - 1);
                float  rms = rsqrtf(ss[r] * (1.0f / 64.0f) + 1.1920929e-07f);
                float  x0 = acc[i][0][r] * rms, x1 = acc[i][1][r] * rms;
                float  x2 = acc[i][2][r] * rms, x3 = acc[i][3][r] * rms;
                float2 t0 = tab[(size_t)s * 32 + l16];        // {cos,sin} i=l16
                float2 t1 = tab[(size_t)s * 32 + 16 + l16];   // i=l16+16
                bf16*  bp = dst + ((size_t)(bb * NH_ + h) * S_ + s) * D_;
                bp[l16]      = (bf16)(x0 * t0.x + x2 * t0.y);
                bp[16 + l16] = (bf16)(x1 * t1.x + x3 * t1.y);
                bp[32 + l16] = (bf16)(x2 * t0.x - x0 * t0.y);
                bp[48 + l16] = (bf16)(x3 * t1.x - x1 * t1.y);
            }
        }
    } else {
        const float l0 = lambdas[0], l1 = lambdas[1];
#pragma unroll
        for (int i = 0; i < 8; ++i) {
            const int m00 = m0 + wm + i * 16 + quad * 4;   // 4 consecutive s
            const int bb  = m00 >> 11, s = m00 & (S_ - 1);
#pragma unroll
            for (int j = 0; j < 4; ++j) {
                const int d = j * 16 + l16;
                bf16x4 pk;
#pragma unroll
                for (int r = 0; r < 4; ++r) {
                    float vm = l0 * acc[i][j][r]
                             + l1 * ve[(size_t)(m00 + r) * H_ + h * 64 + d];
                    pk[r] = (bf16)vm;
                }
                *(bf16x4*)&vtb[((size_t)(bb * NH_ + h) * D_ + d) * S_ + s] = pk;
            }
        }
    }
}

// C[M,N] = A[M,K] @ W[N,K]^T, bf16, BK=64 K-tiles, single-buffered. Tile
// M=128 x N=NT. LDS rows 64 elems XOR-swizzled. Used for output projection
// (EPI=1, NT=64, grid 16x32) with XCD-aware bijective remap.
template <int EPI, int NT>
__global__ __launch_bounds__(256) void gemm_bt(
    const bf16* __restrict__ A, const bf16* __restrict__ W,
    int M, int N, int K,
    float* __restrict__ outF)
{
    constexpr int JN = NT / 32;            // n-subtiles per wave
    __shared__ bf16 Al[128][64];
    __shared__ bf16 Bl[NT][64];
    // remap for the 16x32 launch grid (bijective)
    const int id = blockIdx.x + 16 * blockIdx.y;    // 0..511
    const int rX = id & 7, qX = id >> 3;            // qX in 0..63
    const int m0 = ((rX >> 2) * 16 + (qX >> 2)) * 128;
    const int n0 = ((rX & 3) * 4 + (qX & 3)) * NT;
    const int tid  = threadIdx.x;
    const int lane = tid & 63;
    const int w    = tid >> 6;
    const int quad = lane >> 4;
    const int l16  = lane & 15;
    const int wm   = (w >> 1) * 64;
    const int wn   = (w & 1) * (NT / 2);
    const int r8   = lane >> 3;                 // row within 8-row group
    const int cs   = ((lane & 7) ^ r8) * 8;     // swizzled source col (elems)

    const f32x4 Z4 = {0.f, 0.f, 0.f, 0.f};
    f32x4 acc[4][JN];
#pragma unroll
    for (int i = 0; i < 4; ++i)
#pragma unroll
        for (int j = 0; j < JN; ++j) acc[i][j] = Z4;

    for (int k0 = 0; k0 < K; k0 += 64) {
        {   // A tile: wave w stages rows [w*32, w*32+32)
            const bf16* gA = A + (size_t)(m0 + w * 32 + r8) * K + k0 + cs;
            async16(&Al[w * 32][0],      gA);
            async16(&Al[w * 32 + 8][0],  gA + (size_t)8  * K);
            async16(&Al[w * 32 + 16][0], gA + (size_t)16 * K);
            async16(&Al[w * 32 + 24][0], gA + (size_t)24 * K);
        }
        {
            const bf16* gB = W + (size_t)(n0 + w * 16 + r8) * K + k0 + cs;
            async16(&Bl[w * 16][0],     gB);
            async16(&Bl[w * 16 + 8][0], gB + (size_t)8 * K);
        }
        __syncthreads();
#pragma unroll
        for (int ks = 0; ks < 2; ++ks) {
            bf16x8 af[4], bfg[JN];
#pragma unroll
            for (int i = 0; i < 4; ++i)
                af[i] = *(const bf16x8*)
                    &Al[wm + i * 16 + l16][(((ks << 2) + quad) ^ (l16 & 7)) * 8];
#pragma unroll
            for (int j = 0; j < JN; ++j)
                bfg[j] = *(const bf16x8*)
                    &Bl[wn + j * 16 + l16][(((ks << 2) + quad) ^ (l16 & 7)) * 8];
#pragma unroll
            for (int i = 0; i < 4; ++i)
#pragma unroll
                for (int j = 0; j < JN; ++j)
                    acc[i][j] = mfma16(af[i], bfg[j], acc[i][j]);
        }
        __syncthreads();
    }

#pragma unroll
    for (int i = 0; i < 4; ++i)
#pragma unroll
        for (int j = 0; j < JN; ++j)
#pragma unroll
            for (int r = 0; r < 4; ++r) {
                int m = m0 + wm + i * 16 + quad * 4 + r;
                int n = n0 + wn + j * 16 + l16;
                outF[(size_t)m * N + n] = acc[i][j][r];
            }
}

// ---------------------------------------------------------------------------
// Flash attention, LDS-staged, unpaired balanced flat grid (round-7), NEW:
// P transpose done IN-REGISTER via ds_bpermute (__shfl) instead of an LDS
// round-trip. QK leaves lane (q,l16) holding keys 16nt+4q+{0..3} as 2 u32 of
// packed bf16; the PV A-fragment for dest quad q^ needs keys 8q^+{0..7},
// which live in src lanes l16+32(q^&1) and +16 -> 16 bpermutes + 8 selects,
// one wait, no barrier. Removes Pl (8 KB): LDS 40960 -> 32768 = exactly
// 5 blocks/CU capacity -> all 4 offered blocks resident, chunk chains from
// independent blocks interleave. K/V staging/masking/balance unchanged.
// ---------------------------------------------------------------------------
__global__ __launch_bounds__(256) void attn(
    const bf16* __restrict__ Q, const bf16* __restrict__ Kg,
    const bf16* __restrict__ Vt, bf16* __restrict__ Og)
{
    __shared__ bf16 Kl[2][64][64];
    __shared__ bf16 Vl[2][64][64];

    const int id  = blockIdx.x;            // 0..1023
    const int xcd = id & 7;
    const int jj  = id >> 3;               // 0..127 within-XCD
    const int sH  = jj & 3;                // head slot on this XCD
    const int cC  = jj >> 2;               // 0..31 (CU index under seq dispatch)
    const int bh  = xcd + 8 * sH;          // head id; XCD = bh&7
    const int c2  = (cC + 16) & 31;
    const int qt  = (sH == 0) ? cC : (sH == 1) ? 31 - cC
                  : (sH == 2) ? c2 : 31 - c2;   // per-CU chunk sum == 66

    const int b    = bh >> 4;
    const int h    = bh & 15;
    const int tid  = threadIdx.x;
    const int lane = tid & 63;
    const int w    = tid >> 6;
    const int quad = lane >> 4;
    const int l16  = lane & 15;
    const int l7   = l16 & 7;

    const bf16* Qp = Q  + (size_t)bh * S_ * D_;
    const bf16* Kp = Kg + (size_t)bh * S_ * D_;
    const bf16* Vp = Vt + (size_t)bh * D_ * S_;

    const int srow = lane >> 3;
    const int schk = (lane & 7) ^ (lane >> 3);
    const f32x4 Z4 = {0.f, 0.f, 0.f, 0.f};
    const float C1 = 0.18033688011112042f;     // 0.125*log2(e)
    const float C2 = -11.541560327111707f;     // -8*log2(e)

    // P-transpose shuffle sources: dest quad q^ pulls from lanes sA, sA+16
    const int  sA    = l16 + 32 * (quad & 1);
    const int  sB    = sA + 16;
    const bool selLo = (quad < 2);             // nt = quad>>1 selector

    auto stage = [&](int p, int kb0) {
        const bf16* gK = Kp + (size_t)(kb0 + w * 16 + srow) * D_ + schk * 8;
        async16(&Kl[p][w * 16][0], gK);
        async16(&Kl[p][w * 16 + 8][0], gK + (size_t)8 * D_);
        const bf16* gV = Vp + (size_t)(w * 16 + srow) * S_ + kb0 + schk * 8;
        async16(&Vl[p][w * 16][0], gV);
        async16(&Vl[p][w * 16 + 8][0], gV + (size_t)8 * S_);
    };

    const int qbase = qt * 64 + w * 16;
    const int qi    = qbase + l16;

    const bf16x8 qf0 = *(const bf16x8*)(Qp + (size_t)(qbase + l16) * D_ + quad * 8);
    const bf16x8 qf1 = *(const bf16x8*)(Qp + (size_t)(qbase + l16) * D_ + 32 + quad * 8);

    f32x4 of[4];
#pragma unroll
    for (int dt = 0; dt < 4; ++dt) of[dt] = Z4;
    float lsum = 0.f;

    union W2 { bf16x4 v; unsigned int w[2]; };
    union W8 { unsigned int w[4]; bf16x8 v; };

    const int nch = qt + 1;
    stage(0, 0);
    for (int c = 0; c < nch; ++c) {
        const int p   = c & 1;
        const int kb0 = c * 64;
        __syncthreads();                 // buf[p] ready (prefetch aged 1 phase)
        if (c + 1 < nch) stage(p ^ 1, kb0 + 64);

        float ps = 0.f;
        unsigned int uw[4][2];           // packed P: uw[nt] = keys 16nt+4q+{0..3}
        if (c < qt) {                    // strictly below diagonal: no mask
#pragma unroll
            for (int nt = 0; nt < 4; ++nt) {
                bf16x8 kf0 = *(const bf16x8*)&Kl[p][nt * 16 + l16][(quad ^ l7) * 8];
                bf16x8 kf1 = *(const bf16x8*)&Kl[p][nt * 16 + l16][((quad + 4) ^ l7) * 8];
                f32x4 sacc = Z4;
                sacc = mfma16(kf0, qf0, sacc);
                sacc = mfma16(kf1, qf1, sacc);
                W2 pk;
#pragma unroll
                for (int r = 0; r < 4; ++r) {
                    float pv = exp2f(fmaf(sacc[r], C1, C2));
                    ps += pv;
                    pk.v[r] = (bf16)pv;
                }
                uw[nt][0] = pk.w[0];
                uw[nt][1] = pk.w[1];
            }
        } else {                         // diagonal chunk: causal mask
#pragma unroll
            for (int nt = 0; nt < 4; ++nt) {
                bf16x8 kf0 = *(const bf16x8*)&Kl[p][nt * 16 + l16][(quad ^ l7) * 8];
                bf16x8 kf1 = *(const bf16x8*)&Kl[p][nt * 16 + l16][((quad + 4) ^ l7) * 8];
                f32x4 sacc = Z4;
                sacc = mfma16(kf0, qf0, sacc);
                sacc = mfma16(kf1, qf1, sacc);
                W2 pk;
#pragma unroll
                for (int r = 0; r < 4; ++r) {
                    int   key = kb0 + nt * 16 + quad * 4 + r;
                    float pv  = (key <= qi) ? exp2f(fmaf(sacc[r], C1, C2)) : 0.f;
                    ps += pv;
                    pk.v[r] = (bf16)pv;
                }
                uw[nt][0] = pk.w[0];
                uw[nt][1] = pk.w[1];
            }
        }
        ps += __shfl_xor(ps, 16);
        ps += __shfl_xor(ps, 32);
        lsum += ps;

        // in-register quad transpose: pf0 = keys 8q^..8q^+7, pf1 = +32
        W8 t0, t1;
        {
            unsigned int a0 = __shfl((int)uw[0][0], sA), a1 = __shfl((int)uw[0][1], sA);
            unsigned int a2 = __shfl((int)uw[0][0], sB), a3 = __shfl((int)uw[0][1], sB);
            unsigned int b0 = __shfl((int)uw[1][0], sA), b1 = __shfl((int)uw[1][1], sA);
            unsigned int b2 = __shfl((int)uw[1][0], sB), b3 = __shfl((int)uw[1][1], sB);
            t0.w[0] = selLo ? a0 : b0;  t0.w[1] = selLo ? a1 : b1;
            t0.w[2] = selLo ? a2 : b2;  t0.w[3] = selLo ? a3 : b3;
            unsigned int c0 = __shfl((int)uw[2][0], sA), c1 = __shfl((int)uw[2][1], sA);
            unsigned int c2w = __shfl((int)uw[2][0], sB), c3 = __shfl((int)uw[2][1], sB);
            unsigned int d0 = __shfl((int)uw[3][0], sA), d1 = __shfl((int)uw[3][1], sA);
            unsigned int d2 = __shfl((int)uw[3][0], sB), d3 = __shfl((int)uw[3][1], sB);
            t1.w[0] = selLo ? c0 : d0;  t1.w[1] = selLo ? c1 : d1;
            t1.w[2] = selLo ? c2w : d2; t1.w[3] = selLo ? c3 : d3;
        }
        bf16x8 pf0 = t0.v;
        bf16x8 pf1 = t1.v;
#pragma unroll
        for (int dt = 0; dt < 4; ++dt) {
            bf16x8 vf0 = *(const bf16x8*)&Vl[p][dt * 16 + l16][(quad ^ l7) * 8];
            bf16x8 vf1 = *(const bf16x8*)&Vl[p][dt * 16 + l16][((quad + 4) ^ l7) * 8];
            of[dt] = mfma16(pf0, vf0, of[dt]);
            of[dt] = mfma16(pf1, vf1, of[dt]);
        }
    }

#pragma unroll
    for (int r = 0; r < 4; ++r) {
        float ld = __shfl(lsum, quad * 4 + r);
        float rl = 1.0f / ld;
        int   qq = qbase + quad * 4 + r;
#pragma unroll
        for (int dt = 0; dt < 4; ++dt)
            Og[((size_t)(b * S_ + qq)) * H_ + h * D_ + dt * 16 + l16] =
                (bf16)(of[dt][r] * rl);
    }
}

extern "C" void kernel_launch(void* const* d_in, const int* in_sizes, int n_in,
                              void* d_out, int out_size, void* d_ws, size_t ws_size,
                              hipStream_t stream)
{
    const float* x       = (const float*)d_in[0];
    const float* ve      = (const float*)d_in[1];
    const float* Wqkv    = (const float*)d_in[2];
    const float* Wo      = (const float*)d_in[3];
    const float* lambdas = (const float*)d_in[4];
    float* out = (float*)d_out;

    // d_out (16 MiB) early-phase scratch: xb [0,8M), wqb [8,14M), rope tab [14,14.5M).
    // All die after gemm1; gemm2 overwrites d_out with the final output.
    // ws (32 MiB): qb [0,8M), kb [8,16M), vtb [16,24M), ao [24,32M);
    // wob reuses [0,2M) after attn retires qb.
    char* od = (char*)d_out;
    char* ws = (char*)d_ws;
    const size_t MB = 1024 * 1024;
    bf16*   xb  = (bf16*)(od);
    bf16*   wqb = (bf16*)(od + 8 * MB);
    float2* tab = (float2*)(od + 14 * MB);
    bf16*   qb  = (bf16*)(ws);
    bf16*   kb  = (bf16*)(ws + 8 * MB);
    bf16*   vtb = (bf16*)(ws + 16 * MB);
    bf16*   ao  = (bf16*)(ws + 24 * MB);
    bf16*   wob = (bf16*)(ws);

    // 1) convert x + W_qkv to bf16, build RoPE table (one kernel)
    cvt_main<<<7424, 256, 0, stream>>>(x, Wqkv, xb, wqb, tab);
    // 2) qkv GEMM: 256^2 tiles, 4-phase counted-vmcnt K-loop, XCD-aware remap,
    //    fused RMSNorm + table-RoPE (q,k) + packed lambda-mix (v)
    gemm_qkv<<<dim3(12, 16), 512, 0, stream>>>(
        xb, wqb, qb, kb, vtb, ve, lambdas, (const float2*)tab);
    // 3) LDS-staged flash attention, in-register P transpose, flat grid -> ao
    attn<<<dim3(1024), 256, 0, stream>>>(qb, kb, vtb, ao);
    // 4) convert W_o (into retired qb space)
    cvt_bf16<<<1024, 256, 0, stream>>>(Wo, wob, (H_ * H_) / 4);
    // 5) out = ao @ Wo^T (single-buffered, 128x64 tiles, XCD remap, fp32 out)
    gemm_bt<1, 64><<<dim3(16, 32), 256, 0, stream>>>(
        ao, wob, B_ * S_, H_, H_, out);
}

// Round 9
// 201.648 us; speedup vs baseline: 1.0726x; 1.0726x over previous
//
#include <hip/hip_runtime.h>
#include <math.h>

typedef __bf16 bf16;
typedef __attribute__((ext_vector_type(8))) __bf16 bf16x8;
typedef __attribute__((ext_vector_type(4))) __bf16 bf16x4;
typedef __attribute__((ext_vector_type(4))) float f32x4;

#define B_  2
#define S_  2048
#define H_  1024
#define NH_ 16
#define D_  64

__device__ __forceinline__ f32x4 mfma16(bf16x8 a, bf16x8 b, f32x4 c) {
    return __builtin_amdgcn_mfma_f32_16x16x32_bf16(a, b, c, 0, 0, 0);
}

// async global->LDS, 16B per lane; lds dest = wave-uniform base + lane*16
__device__ __forceinline__ void async16(void* lds, const void* g) {
    __builtin_amdgcn_global_load_lds(
        (const __attribute__((address_space(1))) unsigned int*)g,
        (__attribute__((address_space(3))) unsigned int*)lds, 16, 0, 0);
}

// Merged prep: cvt x -> xb, cvt Wqkv -> wqb, build RoPE table tab[s][i]={cos,sin}
__global__ __launch_bounds__(256) void cvt_main(
    const float* __restrict__ x, const float* __restrict__ wqkv,
    bf16* __restrict__ xb, bf16* __restrict__ wqb, float2* __restrict__ tab)
{
    const int bid = blockIdx.x, tid = threadIdx.x;
    if (bid < 4096) {
        int i = bid * 256 + tid;
        f32x4 v = *(const f32x4*)(x + (size_t)i * 4);
        bf16x4 o; o[0]=(bf16)v[0]; o[1]=(bf16)v[1]; o[2]=(bf16)v[2]; o[3]=(bf16)v[3];
        *(bf16x4*)(xb + (size_t)i * 4) = o;
    } else if (bid < 7168) {
        int i = (bid - 4096) * 256 + tid;
        f32x4 v = *(const f32x4*)(wqkv + (size_t)i * 4);
        bf16x4 o; o[0]=(bf16)v[0]; o[1]=(bf16)v[1]; o[2]=(bf16)v[2]; o[3]=(bf16)v[3];
        *(bf16x4*)(wqb + (size_t)i * 4) = o;
    } else {
        int idx = (bid - 7168) * 256 + tid;      // idx = s*32 + i
        int s = idx >> 5, i = idx & 31;
        float f = exp2f((float)i * (-13.287712379549449f / 32.0f));
        float sn, cs;
        sincosf((float)s * f, &sn, &cs);
        tab[idx] = make_float2(cs, sn);
    }
}

// fp32 -> bf16 bulk convert (W_o), 4 elems/thread
__global__ __launch_bounds__(256) void cvt_bf16(const float* __restrict__ src,
                                                bf16* __restrict__ dst, int n4) {
    int i = blockIdx.x * 256 + threadIdx.x;
    if (i >= n4) return;
    f32x4 v = *(const f32x4*)(src + (size_t)i * 4);
    bf16x4 o; o[0]=(bf16)v[0]; o[1]=(bf16)v[1]; o[2]=(bf16)v[2]; o[3]=(bf16)v[3];
    *(bf16x4*)(dst + (size_t)i * 4) = o;
}

// ---------------------------------------------------------------------------
// qkv GEMM — measured-best round-3 form: 256x256 tile, BK=64, 8 waves
// (2M x 4N), 4-phase K-loop with counted vmcnt, XCD-aware bijective remap.
// Epilogue: fused RMSNorm + table-RoPE (q,k), lambda-mix + transposed v.
// ---------------------------------------------------------------------------
__global__ __launch_bounds__(512, 2) void gemm_qkv(
    const bf16* __restrict__ A, const bf16* __restrict__ W,
    bf16* __restrict__ qb, bf16* __restrict__ kb, bf16* __restrict__ vtb,
    const float* __restrict__ ve, const float* __restrict__ lambdas,
    const float2* __restrict__ tab)
{
    constexpr int K  = H_;        // 1024
    constexpr int NS = K >> 6;    // 16 K-tiles
    __shared__ bf16 Al[2][256][64];
    __shared__ bf16 Bl[2][256][64];
    const int id = blockIdx.x + 12 * blockIdx.y;    // 0..191
    const int rX = id & 7, qX = id >> 3;            // qX in 0..23
    const int m0 = ((rX >> 2) * 8 + qX / 3) * 256;
    const int n0 = ((rX & 3) * 3 + qX % 3) * 256;
    const int tid  = threadIdx.x;
    const int lane = tid & 63;
    const int w    = tid >> 6;          // 0..7
    const int quad = lane >> 4;
    const int l16  = lane & 15;
    const int l7r  = l16 & 7;
    const int wm   = (w >> 2) * 128;    // wave M-offset (0 or 128)
    const int wn   = (w & 3) * 64;      // wave N-offset (0/64/128/192)
    const int r8   = lane >> 3;
    const int cs   = ((lane & 7) ^ r8) * 8;   // swizzled source col (elems)

    // stage half-tile h (0=A0,1=A1,2=B0,3=B1) of K-tile kt into slot sl
    auto stage_half = [&](int sl, int kt, int h) {
        const int k0 = kt << 6;
        if (h < 2) {
            const bf16* g = A + (size_t)(m0 + h * 128 + w * 16 + r8) * K + k0 + cs;
            async16(&Al[sl][h * 128 + w * 16][0],     g);
            async16(&Al[sl][h * 128 + w * 16 + 8][0], g + (size_t)8 * K);
        } else {
            const bf16* g = W + (size_t)(n0 + (h - 2) * 128 + w * 16 + r8) * K + k0 + cs;
            async16(&Bl[sl][(h - 2) * 128 + w * 16][0],     g);
            async16(&Bl[sl][(h - 2) * 128 + w * 16 + 8][0], g + (size_t)8 * K);
        }
    };

    const f32x4 Z4 = {0.f, 0.f, 0.f, 0.f};
    f32x4 acc[8][4];
#pragma unroll
    for (int i = 0; i < 8; ++i)
#pragma unroll
        for (int j = 0; j < 4; ++j) acc[i][j] = Z4;

    // prologue: tile0 fully + tile1's first half (stream position -1)
    stage_half(0, 0, 0); stage_half(0, 0, 1); stage_half(0, 0, 2); stage_half(0, 0, 3);
    stage_half(1, (NS > 1 ? 1 : 0), 0);

    for (int t = 0; t < NS; ++t) {
        const int cur = t & 1;
        const int kt1 = (t + 1 < NS) ? t + 1 : NS - 1;
        const int kt2 = (t + 2 < NS) ? t + 2 : NS - 1;
        bf16x8 aL[4][2], aH[4][2], bq0[2][2], bq1[2][2];

        // ---- phase 0: wait tile t landed (keep next tile's A0 in flight)
        asm volatile("s_waitcnt vmcnt(2)" ::: "memory");
        __builtin_amdgcn_s_barrier();
#pragma unroll
        for (int ks = 0; ks < 2; ++ks) {
#pragma unroll
            for (int i = 0; i < 4; ++i)
                aL[i][ks] = *(const bf16x8*)
                    &Al[cur][wm + i * 16 + l16][(((ks << 2) + quad) ^ l7r) * 8];
#pragma unroll
            for (int j = 0; j < 2; ++j)
                bq0[j][ks] = *(const bf16x8*)
                    &Bl[cur][wn + j * 16 + l16][(((ks << 2) + quad) ^ l7r) * 8];
        }
        stage_half(cur ^ 1, kt1, 1);
        __builtin_amdgcn_s_setprio(1);
#pragma unroll
        for (int ks = 0; ks < 2; ++ks)
#pragma unroll
            for (int i = 0; i < 4; ++i)
#pragma unroll
                for (int j = 0; j < 2; ++j)
                    acc[i][j] = mfma16(aL[i][ks], bq0[j][ks], acc[i][j]);
        __builtin_amdgcn_s_setprio(0);

        // ---- phase 1
        __builtin_amdgcn_s_barrier();
#pragma unroll
        for (int ks = 0; ks < 2; ++ks)
#pragma unroll
            for (int j = 0; j < 2; ++j)
                bq1[j][ks] = *(const bf16x8*)
                    &Bl[cur][wn + 32 + j * 16 + l16][(((ks << 2) + quad) ^ l7r) * 8];
        stage_half(cur ^ 1, kt1, 2);
        __builtin_amdgcn_s_setprio(1);
#pragma unroll
        for (int ks = 0; ks < 2; ++ks)
#pragma unroll
            for (int i = 0; i < 4; ++i)
#pragma unroll
                for (int j = 0; j < 2; ++j)
                    acc[i][2 + j] = mfma16(aL[i][ks], bq1[j][ks], acc[i][2 + j]);
        __builtin_amdgcn_s_setprio(0);

        // ---- phase 2
        __builtin_amdgcn_s_barrier();
#pragma unroll
        for (int ks = 0; ks < 2; ++ks)
#pragma unroll
            for (int i = 0; i < 4; ++i)
                aH[i][ks] = *(const bf16x8*)
                    &Al[cur][wm + 64 + i * 16 + l16][(((ks << 2) + quad) ^ l7r) * 8];
        stage_half(cur ^ 1, kt1, 3);
        __builtin_amdgcn_s_setprio(1);
#pragma unroll
        for (int ks = 0; ks < 2; ++ks)
#pragma unroll
            for (int i = 0; i < 4; ++i)
#pragma unroll
                for (int j = 0; j < 2; ++j)
                    acc[4 + i][j] = mfma16(aH[i][ks], bq0[j][ks], acc[4 + i][j]);
        __builtin_amdgcn_s_setprio(0);

        // ---- phase 3
        __builtin_amdgcn_s_barrier();
        stage_half(cur, kt2, 0);
        __builtin_amdgcn_s_setprio(1);
#pragma unroll
        for (int ks = 0; ks < 2; ++ks)
#pragma unroll
            for (int i = 0; i < 4; ++i)
#pragma unroll
                for (int j = 0; j < 2; ++j)
                    acc[4 + i][2 + j] = mfma16(aH[i][ks], bq1[j][ks], acc[4 + i][2 + j]);
        __builtin_amdgcn_s_setprio(0);
    }
    asm volatile("s_waitcnt vmcnt(0)" ::: "memory");   // drain clamped tail stages

    // ---- fused epilogue
    const int nbase = n0 + wn;              // wave-uniform, 64-aligned
    const int which = nbase >> 10;          // 0=q 1=k 2=v
    const int h     = (nbase & (H_ - 1)) >> 6;
    if (which < 2) {
        bf16* dst = which ? kb : qb;
#pragma unroll
        for (int i = 0; i < 8; ++i) {
            float ss[4];
#pragma unroll
            for (int r = 0; r < 4; ++r)
                ss[r] = acc[i][0][r] * acc[i][0][r] + acc[i][1][r] * acc[i][1][r]
                      + acc[i][2][r] * acc[i][2][r] + acc[i][3][r] * acc[i][3][r];
#pragma unroll
            for (int r = 0; r < 4; ++r) {
                ss[r] += __shfl_xor(ss[r], 1);
                ss[r] += __shfl_xor(ss[r], 2);
                ss[r] += __shfl_xor(ss[r], 4);
                ss[r] += __shfl_xor(ss[r], 8);
            }
#pragma unroll
            for (int r = 0; r < 4; ++r) {
                int    m   = m0 + wm + i * 16 + quad * 4 + r;
                int    bb  = m >> 11, s = m & (S_ - 1);
                float  rms = rsqrtf(ss[r] * (1.0f / 64.0f) + 1.1920929e-07f);
                float  x0 = acc[i][0][r] * rms, x1 = acc[i][1][r] * rms;
                float  x2 = acc[i][2][r] * rms, x3 = acc[i][3][r] * rms;
                float2 t0 = tab[(size_t)s * 32 + l16];        // {cos,sin} i=l16
                float2 t1 = tab[(size_t)s * 32 + 16 + l16];   // i=l16+16
                bf16*  bp = dst + ((size_t)(bb * NH_ + h) * S_ + s) * D_;
                bp[l16]      = (bf16)(x0 * t0.x + x2 * t0.y);
                bp[16 + l16] = (bf16)(x1 * t1.x + x3 * t1.y);
                bp[32 + l16] = (bf16)(x2 * t0.x - x0 * t0.y);
                bp[48 + l16] = (bf16)(x3 * t1.x - x1 * t1.y);
            }
        }
    } else {
        const float l0 = lambdas[0], l1 = lambdas[1];
#pragma unroll
        for (int i = 0; i < 8; ++i) {
            const int m00 = m0 + wm + i * 16 + quad * 4;   // 4 consecutive s
            const int bb  = m00 >> 11, s = m00 & (S_ - 1);
#pragma unroll
            for (int j = 0; j < 4; ++j) {
                const int d = j * 16 + l16;
                bf16x4 pk;
#pragma unroll
                for (int r = 0; r < 4; ++r) {
                    float vm = l0 * acc[i][j][r]
                             + l1 * ve[(size_t)(m00 + r) * H_ + h * 64 + d];
                    pk[r] = (bf16)vm;
                }
                *(bf16x4*)&vtb[((size_t)(bb * NH_ + h) * D_ + d) * S_ + s] = pk;
            }
        }
    }
}

// ---------------------------------------------------------------------------
// Output projection GEMM: out[4096,1024] = ao @ Wo^T. 128x64 tiles, BK=64,
// NEW: double-buffered LDS + counted-vmcnt 2-phase K-loop (R2-validated
// mechanism; gemm2's geometry avoids R1's failure modes: 512 blocks = exactly
// one residency round (no tail), LDS 48 KB -> 3 blocks/CU capacity >= the 2
// offered). Per tile: vmcnt(6) keeps next tile's 6 loads in flight across the
// compute; stage of tile t+2 goes into the just-read slot after the barrier
// that proves all waves' ds_reads retired. Tail: t=NS-2 skips its stage, so
// t=NS-1 must drain vmcnt(0) (the skipped stage would leave stage(NS-1)
// uncounted by vmcnt(6)). XCD-aware bijective remap kept.
// ---------------------------------------------------------------------------
__global__ __launch_bounds__(256) void gemm_o(
    const bf16* __restrict__ A, const bf16* __restrict__ W,
    float* __restrict__ outF)
{
    constexpr int K  = H_;        // 1024
    constexpr int N  = H_;
    constexpr int NS = K >> 6;    // 16
    __shared__ bf16 Al[2][128][64];
    __shared__ bf16 Bl[2][64][64];
    const int id = blockIdx.x + 16 * blockIdx.y;    // 0..511
    const int rX = id & 7, qX = id >> 3;            // qX in 0..63
    const int m0 = ((rX >> 2) * 16 + (qX >> 2)) * 128;
    const int n0 = ((rX & 3) * 4 + (qX & 3)) * 64;
    const int tid  = threadIdx.x;
    const int lane = tid & 63;
    const int w    = tid >> 6;
    const int quad = lane >> 4;
    const int l16  = lane & 15;
    const int l7r  = l16 & 7;
    const int wm   = (w >> 1) * 64;
    const int wn   = (w & 1) * 32;
    const int r8   = lane >> 3;                 // row within 8-row group
    const int cs   = ((lane & 7) ^ r8) * 8;     // swizzled source col (elems)

    auto stage = [&](int sl, int k0) {          // 6 async16 per wave
        const bf16* gA = A + (size_t)(m0 + w * 32 + r8) * K + k0 + cs;
        async16(&Al[sl][w * 32][0],      gA);
        async16(&Al[sl][w * 32 + 8][0],  gA + (size_t)8  * K);
        async16(&Al[sl][w * 32 + 16][0], gA + (size_t)16 * K);
        async16(&Al[sl][w * 32 + 24][0], gA + (size_t)24 * K);
        const bf16* gB = W + (size_t)(n0 + w * 16 + r8) * K + k0 + cs;
        async16(&Bl[sl][w * 16][0],     gB);
        async16(&Bl[sl][w * 16 + 8][0], gB + (size_t)8 * K);
    };

    const f32x4 Z4 = {0.f, 0.f, 0.f, 0.f};
    f32x4 acc[4][2];
#pragma unroll
    for (int i = 0; i < 4; ++i)
#pragma unroll
        for (int j = 0; j < 2; ++j) acc[i][j] = Z4;

    stage(0, 0);
    stage(1, 64);

    for (int t = 0; t < NS; ++t) {
        const int cur = t & 1;
        if (t >= NS - 1) { asm volatile("s_waitcnt vmcnt(0)" ::: "memory"); }
        else             { asm volatile("s_waitcnt vmcnt(6)" ::: "memory"); }
        __builtin_amdgcn_s_barrier();           // buf[cur] landed, prev reads done

        bf16x8 af[4][2], bfg[2][2];
#pragma unroll
        for (int ks = 0; ks < 2; ++ks) {
#pragma unroll
            for (int i = 0; i < 4; ++i)
                af[i][ks] = *(const bf16x8*)
                    &Al[cur][wm + i * 16 + l16][(((ks << 2) + quad) ^ l7r) * 8];
#pragma unroll
            for (int j = 0; j < 2; ++j)
                bfg[j][ks] = *(const bf16x8*)
                    &Bl[cur][wn + j * 16 + l16][(((ks << 2) + quad) ^ l7r) * 8];
        }
        __builtin_amdgcn_s_setprio(1);
#pragma unroll
        for (int i = 0; i < 4; ++i)
#pragma unroll
            for (int j = 0; j < 2; ++j)
                acc[i][j] = mfma16(af[i][0], bfg[j][0], acc[i][j]);
        __builtin_amdgcn_s_setprio(0);

        __builtin_amdgcn_s_barrier();           // all waves' ds_reads of cur retired
        if (t + 2 < NS) stage(cur, (t + 2) << 6);
        __builtin_amdgcn_s_setprio(1);
#pragma unroll
        for (int i = 0; i < 4; ++i)
#pragma unroll
            for (int j = 0; j < 2; ++j)
                acc[i][j] = mfma16(af[i][1], bfg[j][1], acc[i][j]);
        __builtin_amdgcn_s_setprio(0);
    }
    asm volatile("s_waitcnt vmcnt(0)" ::: "memory");

#pragma unroll
    for (int i = 0; i < 4; ++i)
#pragma unroll
        for (int j = 0; j < 2; ++j)
#pragma unroll
            for (int r = 0; r < 4; ++r) {
                int m = m0 + wm + i * 16 + quad * 4 + r;
                int n = n0 + wn + j * 16 + l16;
                outF[(size_t)m * N + n] = acc[i][j][r];
            }
}

// ---------------------------------------------------------------------------
// Flash attention — round-7 body (best measured: 53.3 us). LDS-staged K/V,
// double-buffered, per-wave P transpose through LDS (Pl), unpaired balanced
// flat grid: id&7 = XCD, bh = xcd+8*sH keeps each head's 32 blocks on one XCD;
// qt assignment gives every aligned 4-block group a chunk sum of 66.
// Static max=8, swapped-operand QK, diagonal-only causal masking.
// ---------------------------------------------------------------------------
__global__ __launch_bounds__(256) void attn(
    const bf16* __restrict__ Q, const bf16* __restrict__ Kg,
    const bf16* __restrict__ Vt, bf16* __restrict__ Og)
{
    __shared__ bf16 Kl[2][64][64];
    __shared__ bf16 Vl[2][64][64];
    __shared__ bf16 Pl[4][16][64];

    const int id  = blockIdx.x;            // 0..1023
    const int xcd = id & 7;
    const int jj  = id >> 3;               // 0..127 within-XCD
    const int sH  = jj & 3;                // head slot on this XCD
    const int cC  = jj >> 2;               // 0..31 (CU index under seq dispatch)
    const int bh  = xcd + 8 * sH;          // head id; XCD = bh&7
    const int c2  = (cC + 16) & 31;
    const int qt  = (sH == 0) ? cC : (sH == 1) ? 31 - cC
                  : (sH == 2) ? c2 : 31 - c2;   // per-CU chunk sum == 66

    const int b    = bh >> 4;
    const int h    = bh & 15;
    const int tid  = threadIdx.x;
    const int lane = tid & 63;
    const int w    = tid >> 6;
    const int quad = lane >> 4;
    const int l16  = lane & 15;
    const int l7   = l16 & 7;

    const bf16* Qp = Q  + (size_t)bh * S_ * D_;
    const bf16* Kp = Kg + (size_t)bh * S_ * D_;
    const bf16* Vp = Vt + (size_t)bh * D_ * S_;

    const int srow = lane >> 3;
    const int schk = (lane & 7) ^ (lane >> 3);
    const f32x4 Z4 = {0.f, 0.f, 0.f, 0.f};
    const float C1 = 0.18033688011112042f;     // 0.125*log2(e)
    const float C2 = -11.541560327111707f;     // -8*log2(e)

    auto stage = [&](int p, int kb0) {
        const bf16* gK = Kp + (size_t)(kb0 + w * 16 + srow) * D_ + schk * 8;
        async16(&Kl[p][w * 16][0], gK);
        async16(&Kl[p][w * 16 + 8][0], gK + (size_t)8 * D_);
        const bf16* gV = Vp + (size_t)(w * 16 + srow) * S_ + kb0 + schk * 8;
        async16(&Vl[p][w * 16][0], gV);
        async16(&Vl[p][w * 16 + 8][0], gV + (size_t)8 * S_);
    };

    const int qbase = qt * 64 + w * 16;
    const int qi    = qbase + l16;

    const bf16x8 qf0 = *(const bf16x8*)(Qp + (size_t)(qbase + l16) * D_ + quad * 8);
    const bf16x8 qf1 = *(const bf16x8*)(Qp + (size_t)(qbase + l16) * D_ + 32 + quad * 8);

    f32x4 of[4];
#pragma unroll
    for (int dt = 0; dt < 4; ++dt) of[dt] = Z4;
    float lsum = 0.f;

    const int nch = qt + 1;
    stage(0, 0);
    for (int c = 0; c < nch; ++c) {
        const int p   = c & 1;
        const int kb0 = c * 64;
        __syncthreads();                 // buf[p] ready (prefetch aged 1 phase)
        if (c + 1 < nch) stage(p ^ 1, kb0 + 64);

        float ps = 0.f;
        if (c < qt) {                    // strictly below diagonal: no mask
#pragma unroll
            for (int nt = 0; nt < 4; ++nt) {
                bf16x8 kf0 = *(const bf16x8*)&Kl[p][nt * 16 + l16][(quad ^ l7) * 8];
                bf16x8 kf1 = *(const bf16x8*)&Kl[p][nt * 16 + l16][((quad + 4) ^ l7) * 8];
                f32x4 sacc = Z4;
                sacc = mfma16(kf0, qf0, sacc);
                sacc = mfma16(kf1, qf1, sacc);
                bf16x4 pk;
#pragma unroll
                for (int r = 0; r < 4; ++r) {
                    float pv = exp2f(fmaf(sacc[r], C1, C2));
                    ps += pv;
                    pk[r] = (bf16)pv;
                }
                *(bf16x4*)&Pl[w][l16][((nt * 2 + (quad >> 1)) ^ l7) * 8 + (quad & 1) * 4] = pk;
            }
        } else {                         // diagonal chunk: causal mask
#pragma unroll
            for (int nt = 0; nt < 4; ++nt) {
                bf16x8 kf0 = *(const bf16x8*)&Kl[p][nt * 16 + l16][(quad ^ l7) * 8];
                bf16x8 kf1 = *(const bf16x8*)&Kl[p][nt * 16 + l16][((quad + 4) ^ l7) * 8];
                f32x4 sacc = Z4;
                sacc = mfma16(kf0, qf0, sacc);
                sacc = mfma16(kf1, qf1, sacc);
                bf16x4 pk;
#pragma unroll
                for (int r = 0; r < 4; ++r) {
                    int   key = kb0 + nt * 16 + quad * 4 + r;
                    float pv  = (key <= qi) ? exp2f(fmaf(sacc[r], C1, C2)) : 0.f;
                    ps += pv;
                    pk[r] = (bf16)pv;
                }
                *(bf16x4*)&Pl[w][l16][((nt * 2 + (quad >> 1)) ^ l7) * 8 + (quad & 1) * 4] = pk;
            }
        }
        ps += __shfl_xor(ps, 16);
        ps += __shfl_xor(ps, 32);
        lsum += ps;

        bf16x8 pf0 = *(const bf16x8*)&Pl[w][l16][(quad ^ l7) * 8];
        bf16x8 pf1 = *(const bf16x8*)&Pl[w][l16][((quad + 4) ^ l7) * 8];
#pragma unroll
        for (int dt = 0; dt < 4; ++dt) {
            bf16x8 vf0 = *(const bf16x8*)&Vl[p][dt * 16 + l16][(quad ^ l7) * 8];
            bf16x8 vf1 = *(const bf16x8*)&Vl[p][dt * 16 + l16][((quad + 4) ^ l7) * 8];
            of[dt] = mfma16(pf0, vf0, of[dt]);
            of[dt] = mfma16(pf1, vf1, of[dt]);
        }
    }

#pragma unroll
    for (int r = 0; r < 4; ++r) {
        float ld = __shfl(lsum, quad * 4 + r);
        float rl = 1.0f / ld;
        int   qq = qbase + quad * 4 + r;
#pragma unroll
        for (int dt = 0; dt < 4; ++dt)
            Og[((size_t)(b * S_ + qq)) * H_ + h * D_ + dt * 16 + l16] =
                (bf16)(of[dt][r] * rl);
    }
}

extern "C" void kernel_launch(void* const* d_in, const int* in_sizes, int n_in,
                              void* d_out, int out_size, void* d_ws, size_t ws_size,
                              hipStream_t stream)
{
    const float* x       = (const float*)d_in[0];
    const float* ve      = (const float*)d_in[1];
    const float* Wqkv    = (const float*)d_in[2];
    const float* Wo      = (const float*)d_in[3];
    const float* lambdas = (const float*)d_in[4];
    float* out = (float*)d_out;

    // d_out (16 MiB) early-phase scratch: xb [0,8M), wqb [8,14M), rope tab [14,14.5M).
    // All die after gemm1; gemm2 overwrites d_out with the final output.
    // ws (32 MiB): qb [0,8M), kb [8,16M), vtb [16,24M), ao [24,32M);
    // wob reuses [0,2M) after attn retires qb.
    char* od = (char*)d_out;
    char* ws = (char*)d_ws;
    const size_t MB = 1024 * 1024;
    bf16*   xb  = (bf16*)(od);
    bf16*   wqb = (bf16*)(od + 8 * MB);
    float2* tab = (float2*)(od + 14 * MB);
    bf16*   qb  = (bf16*)(ws);
    bf16*   kb  = (bf16*)(ws + 8 * MB);
    bf16*   vtb = (bf16*)(ws + 16 * MB);
    bf16*   ao  = (bf16*)(ws + 24 * MB);
    bf16*   wob = (bf16*)(ws);

    // 1) convert x + W_qkv to bf16, build RoPE table (one kernel)
    cvt_main<<<7424, 256, 0, stream>>>(x, Wqkv, xb, wqb, tab);
    // 2) qkv GEMM: 256^2 tiles, 4-phase counted-vmcnt K-loop, XCD-aware remap,
    //    fused RMSNorm + table-RoPE (q,k) + packed lambda-mix (v)
    gemm_qkv<<<dim3(12, 16), 512, 0, stream>>>(
        xb, wqb, qb, kb, vtb, ve, lambdas, (const float2*)tab);
    // 3) LDS-staged flash attention (round-7 best body), flat grid -> ao
    attn<<<dim3(1024), 256, 0, stream>>>(qb, kb, vtb, ao);
    // 4) convert W_o (into retired qb space)
    cvt_bf16<<<1024, 256, 0, stream>>>(Wo, wob, (H_ * H_) / 4);
    // 5) out = ao @ Wo^T (double-buffered counted-vmcnt 2-phase, fp32 out)
    gemm_o<<<dim3(16, 32), 256, 0, stream>>>(ao, wob, out);
}